// Round 7
// baseline (165.252 us; speedup 1.0000x reference)
//
#include <hip/hip_runtime.h>
#include <stdint.h>

#define B 8
#define F 8192
#define C 256
#define K 4
#define P (F / 4)     // 2048
#define CAP 16        // max tracked incoming collapsed faces per target
#define NB 2048       // linear bins over per-batch [lo, hi]
#define BF (B * F)
#define CCAP 1024     // boundary-bin candidate capacity (pop ~ O(10-20))

typedef float f32x4 __attribute__((ext_vector_type(4)));

// Monotone, deterministic linear bin — identical in every block.
__device__ __forceinline__ int binOf(float v, float lo, float scale) {
    int bin = (int)((v - lo) * scale);
    return bin < 0 ? 0 : (bin > NB - 1 ? NB - 1 : bin);
}

// ---------------------------------------------------------------------------
// kW: one wave per face — gather K=4 ring rows, mean, L2 norm^2 -> w.
// (sqrt dropped: monotone — validated r4/r5.) Block->batch swizzle:
// blockIdx&7 = batch == XCD. cnt/flag zeroing gone (no global scatter now).
// ---------------------------------------------------------------------------
__global__ __launch_bounds__(256) void kW(const float* __restrict__ feat,
                                          const int* __restrict__ ring,
                                          float* __restrict__ w) {
    const int b     = blockIdx.x & 7;                       // batch == XCD
    const int inner = blockIdx.x >> 3;                      // [0, 2048)
    const int wid   = b * F + inner * 4 + (threadIdx.x >> 6);
    const int lane  = threadIdx.x & 63;

    const int rbase = wid * K;
    const int r0 = ring[rbase + 0], r1 = ring[rbase + 1];
    const int r2 = ring[rbase + 2], r3 = ring[rbase + 3];
    const float4* f4 = (const float4*)feat;
    const size_t base = (size_t)b * F;
    const int    CW   = C / 4;
    const float4 v0 = f4[(base + r0) * CW + lane];
    const float4 v1 = f4[(base + r1) * CW + lane];
    const float4 v2 = f4[(base + r2) * CW + lane];
    const float4 v3 = f4[(base + r3) * CW + lane];

    float4 a;
    a.x = (v0.x + v1.x) + (v2.x + v3.x);
    a.y = (v0.y + v1.y) + (v2.y + v3.y);
    a.z = (v0.z + v1.z) + (v2.z + v3.z);
    a.w = (v0.w + v1.w) + (v2.w + v3.w);
    float s = (a.x * a.x + a.y * a.y + a.z * a.z + a.w * a.w) * 0.0625f;
#pragma unroll
    for (int off = 32; off > 0; off >>= 1) s += __shfl_down(s, off, 64);
    if (lane == 0) w[wid] = s;                              // norm^2 (monotone)
}

// ---------------------------------------------------------------------------
// kM: fused threshold + LOCAL incoming-list build + merge/write.
// 256 blocks x 256 thr; block g: batch b = g&7 (== XCD), owns faces
// [gg*256, gg*256+256) with gg = g>>3. Every block:
//   1. reads its batch's FULL w slice into registers (val[32]; identical
//      layout in all 32 blocks of a batch -> bit-identical phases 2-4);
//   2. min/max + NB-bin histogram + scan -> (T, R)  [round-6 validated];
//   3. derives the ENTIRE collapsed set: bin<T faces compacted to col[],
//      bin==T candidates exact-ranked (integer keys, order-independent),
//      rank<R appended. Marks own flagged faces in sflag.
//   4. scans the 2048 collapsed faces' adjacency; targets in own range
//      feed LDS lists (full count in lcnt, CAP-capped list) — replaces the
//      global flag/cnt/srcs arrays and ALL device-scope atomics;
//   5. merge phase: one wave per own face — own row + LDS-broadcast source
//      rows, normalize, NT store.
// LDS ~34 KB (col aliases h) -> 4 blocks/CU, 16 waves/CU.
// ---------------------------------------------------------------------------
__global__ __launch_bounds__(256) void kM(const float* __restrict__ feat,
                                          const float* __restrict__ w,
                                          const int* __restrict__ adj,
                                          float* __restrict__ out) {
    __shared__ int h[NB];                                   // 8 KiB (-> col)
    __shared__ unsigned long long carr[CCAP];               // 8 KiB
    __shared__ int lists[256 * CAP];                        // 16 KiB
    __shared__ int lcnt[256];                               // 1 KiB
    __shared__ int sflag[256];                              // 1 KiB
    __shared__ unsigned int redmn[4], redmx[4];
    __shared__ int wsum[4];
    __shared__ unsigned int slo, shi;
    __shared__ int sT, sR, sncol, sncar;

    const int g    = blockIdx.x;
    const int b    = g & 7;                                 // batch == XCD
    const int gg   = g >> 3;                                // block-in-batch [0,32)
    const int t    = threadIdx.x;
    const int lane = t & 63, wv = t >> 6;

    if (t == 0) { sncol = 0; sncar = 0; }
    lcnt[t]  = 0;
    sflag[t] = 0;

    // ---- phase 1: full batch w into registers + min/max ----
    float val[32];
    unsigned int mn = 0xFFFFFFFFu, mx = 0u;
#pragma unroll
    for (int k = 0; k < 32; ++k) {
        val[k] = w[b * F + k * 256 + t];                    // face = k*256+t
        const unsigned int u = __float_as_uint(val[k]);     // w>=0: bit-monotone
        mn = mn < u ? mn : u;
        mx = mx > u ? mx : u;
    }
#pragma unroll
    for (int off = 32; off > 0; off >>= 1) {
        const unsigned int o1 = __shfl_xor(mn, off, 64); mn = mn < o1 ? mn : o1;
        const unsigned int o2 = __shfl_xor(mx, off, 64); mx = mx > o2 ? mx : o2;
    }
    if (lane == 0) { redmn[wv] = mn; redmx[wv] = mx; }
    for (int i = t; i < NB; i += 256) h[i] = 0;
    __syncthreads();                                        // [1]
    if (t == 0) {
        unsigned int a = redmn[0], c = redmx[0];
        for (int i = 1; i < 4; ++i) {
            a = a < redmn[i] ? a : redmn[i];
            c = c > redmx[i] ? c : redmx[i];
        }
        slo = a; shi = c;
    }
    __syncthreads();                                        // [2]
    const float lo    = __uint_as_float(slo);
    const float hi    = __uint_as_float(shi);
    const float scale = (float)(NB - 2) / fmaxf(hi - lo, 1e-30f);

    // ---- phase 2: histogram + scan -> (T, R) ----
#pragma unroll
    for (int k = 0; k < 32; ++k) atomicAdd(&h[binOf(val[k], lo, scale)], 1);
    __syncthreads();                                        // [3]
    int s = 0;
#pragma unroll
    for (int i = 0; i < 8; ++i) s += h[t * 8 + i];          // 8 bins/thread
    int incl = s;
#pragma unroll
    for (int off = 1; off < 64; off <<= 1) {
        const int u = __shfl_up(incl, off, 64);
        if (lane >= off) incl += u;
    }
    if (lane == 63) wsum[wv] = incl;
    __syncthreads();                                        // [4]
    int add = 0;
    for (int i = 0; i < wv; ++i) add += wsum[i];
    const int inclT = incl + add;
    const int exclT = inclT - s;
    if (P - 1 >= exclT && P - 1 < inclT) {                  // exactly one thread
        int c = exclT;
#pragma unroll
        for (int i = 0; i < 8; ++i) {
            const int bin = t * 8 + i;
            const int hv  = h[bin];
            if (P - 1 < c + hv) { sT = bin; sR = P - c; break; }
            c += hv;
        }
    }
    __syncthreads();                                        // [5]  (h now dead)
    const int T = sT, R = sR;
    int* col = h;                                           // alias: 2048 slots

    // ---- phase 3: derive collapsed set (identical in all blocks) ----
#pragma unroll
    for (int k = 0; k < 32; ++k) {
        const int bin = binOf(val[k], lo, scale);
        if (bin < T) {
            const int pos = atomicAdd(&sncol, 1);           // LDS atomic
            col[pos] = k * 256 + t;
            if (k == gg) sflag[t] = 1;                      // own face collapsed
        } else if (bin == T) {
            const int pos = atomicAdd(&sncar, 1);
            if (pos < CCAP)
                carr[pos] = ((unsigned long long)__float_as_uint(val[k]) << 32) |
                            (uint32_t)(k * 256 + t);
        }
    }
    __syncthreads();                                        // [6]
    const int n = sncar < CCAP ? sncar : CCAP;
    for (int i = t; i < n; i += 256) {                      // exact rank (keys distinct)
        const unsigned long long my = carr[i];
        int rank = 0;
        for (int j = 0; j < n; ++j) rank += (carr[j] < my) ? 1 : 0;
        if (rank < R) {
            const int f   = (int)(uint32_t)my;
            const int pos = atomicAdd(&sncol, 1);
            col[pos] = f;
            if ((f >> 8) == gg) sflag[f & 255] = 1;
        }
    }
    __syncthreads();                                        // [7]

    // ---- phase 4: adjacency scan -> local incoming lists ----
    const int ncol = sncol < 2048 ? sncol : 2048;           // == P
    for (int i = t; i < ncol; i += 256) {
        const int c    = col[i];
        const size_t a = (size_t)(b * F + c) * 3;
#pragma unroll
        for (int j = 0; j < 3; ++j) {
            const int tgt = adj[a + j];
            if ((tgt >> 8) == gg) {                         // target in own range
                const int fl  = tgt & 255;
                const int pos = atomicAdd(&lcnt[fl], 1);    // LDS atomic
                if (pos < CAP) lists[fl * CAP + pos] = c;
            }
        }
    }
    __syncthreads();                                        // [8]

    // ---- phase 5: merge + normalize + erase, one wave per own face ----
    const int CW = C / 4;
    const float inv3 = 1.0f / 3.0f;
    for (int j = 0; j < 64; ++j) {
        const int fl = wv * 64 + j;                         // local face [0,256)
        const int fg = b * F + gg * 256 + fl;               // global face
        f32x4* drow = (f32x4*)(out + (size_t)fg * C);
        if (sflag[fl]) {                                    // erased face
            f32x4 z = {0.f, 0.f, 0.f, 0.f};
            __builtin_nontemporal_store(z, &drow[lane]);
            continue;
        }
        const int m  = lcnt[fl];
        const int mm = m < CAP ? m : CAP;
        float4 acc = ((const float4*)(feat + (size_t)fg * C))[lane];
        for (int i = 0; i < mm; ++i) {
            const int c = lists[fl * CAP + i];              // LDS broadcast
            const float4 v = ((const float4*)(feat + (size_t)(b * F + c) * C))[lane];
            acc.x += v.x * inv3; acc.y += v.y * inv3;
            acc.z += v.z * inv3; acc.w += v.w * inv3;
        }
        const float inv = 1.0f / (1.0f + (float)m);
        f32x4 r;
        r.x = acc.x * inv; r.y = acc.y * inv;
        r.z = acc.z * inv; r.w = acc.w * inv;
        __builtin_nontemporal_store(r, &drow[lane]);
    }
}

extern "C" void kernel_launch(void* const* d_in, const int* in_sizes, int n_in,
                              void* d_out, int out_size, void* d_ws, size_t ws_size,
                              hipStream_t stream) {
    const float* feat = (const float*)d_in[0];
    const int*   adj  = (const int*)d_in[1];
    const int*   ring = (const int*)d_in[2];
    float* out = (float*)d_out;

    float* w = (float*)d_ws;                                // B*F floats only

    kW<<<BF / 4, 256, 0, stream>>>(feat, ring, w);
    kM<<<256, 256, 0, stream>>>(feat, w, adj, out);
}

// Round 8
// 153.686 us; speedup vs baseline: 1.0753x; 1.0753x over previous
//
#include <hip/hip_runtime.h>
#include <stdint.h>

#define B 8
#define F 8192
#define C 256
#define K 4
#define P (F / 4)     // 2048
#define CAP 16        // max tracked incoming collapsed faces per target
#define NB 4096       // linear bins over per-batch [lo, hi]
#define BF (B * F)
#define CCAP 1024     // leader LDS candidate capacity (bin==T pop ~ O(10))

typedef float f32x4 __attribute__((ext_vector_type(4)));

// Monotone, deterministic linear bin — identical expression in every block.
__device__ __forceinline__ int binOf(float v, float lo, float scale) {
    int bin = (int)((v - lo) * scale);
    return bin < 0 ? 0 : (bin > NB - 1 ? NB - 1 : bin);
}

// ---------------------------------------------------------------------------
// kW: one wave per face — gather K=4 ring rows, mean, L2 norm^2 -> w.
// (sqrt dropped: monotone — r4/r5.) Lane 0 zeroes cnt/flag.
// 256 MB gathered reads at ~6.4 TB/s blended => BW-saturated; leave alone.
// ---------------------------------------------------------------------------
__global__ __launch_bounds__(256) void kW(const float* __restrict__ feat,
                                          const int* __restrict__ ring,
                                          float* __restrict__ w,
                                          int* __restrict__ cnt,
                                          int* __restrict__ flag) {
    const int b     = blockIdx.x & 7;                       // batch == XCD
    const int inner = blockIdx.x >> 3;                      // [0, 2048)
    const int wid   = b * F + inner * 4 + (threadIdx.x >> 6);
    const int lane  = threadIdx.x & 63;

    const int rbase = wid * K;
    const int r0 = ring[rbase + 0], r1 = ring[rbase + 1];
    const int r2 = ring[rbase + 2], r3 = ring[rbase + 3];
    const float4* f4 = (const float4*)feat;
    const size_t base = (size_t)b * F;
    const int    CW   = C / 4;
    const float4 v0 = f4[(base + r0) * CW + lane];
    const float4 v1 = f4[(base + r1) * CW + lane];
    const float4 v2 = f4[(base + r2) * CW + lane];
    const float4 v3 = f4[(base + r3) * CW + lane];

    float4 a;
    a.x = (v0.x + v1.x) + (v2.x + v3.x);
    a.y = (v0.y + v1.y) + (v2.y + v3.y);
    a.z = (v0.z + v1.z) + (v2.z + v3.z);
    a.w = (v0.w + v1.w) + (v2.w + v3.w);
    float s = (a.x * a.x + a.y * a.y + a.z * a.z + a.w * a.w) * 0.0625f;
#pragma unroll
    for (int off = 32; off > 0; off >>= 1) s += __shfl_down(s, off, 64);
    if (lane == 0) {
        w[wid]    = s;                                      // norm^2 (monotone)
        cnt[wid]  = 0;
        flag[wid] = 0;
    }
}

// ---------------------------------------------------------------------------
// kFS: fused threshold + scatter + boundary-select (round-6, validated).
// 256 blocks x 256 thr; each block redundantly recomputes its batch's
// (T, R) from the full 32 KB w slice (bit-deterministic: fp min/max exact,
// hist/scan integer); scatters its own 256 faces at full GPU width; leader
// block per batch exact-ranks the bin==T boundary candidates.
// ---------------------------------------------------------------------------
__global__ __launch_bounds__(256) void kFS(const float* __restrict__ w,
                                           const int* __restrict__ adj,
                                           int* __restrict__ flag,
                                           int* __restrict__ cnt,
                                           int* __restrict__ srcs) {
    __shared__ int h[NB];                                   // 16 KiB
    __shared__ unsigned long long carr[CCAP];               // 8 KiB
    __shared__ unsigned int redmn[4], redmx[4];
    __shared__ int wsum[4];
    __shared__ unsigned int slo, shi;
    __shared__ int sT, sR, scnt;
    const int g    = blockIdx.x;
    const int b    = g >> 5;                                // batch
    const int gg   = g & 31;                                // block-in-batch
    const int t    = threadIdx.x;
    const int lane = t & 63, wv = t >> 6;

    if (t == 0) scnt = 0;
    for (int i = t; i < NB; i += 256) h[i] = 0;

    float val[32];
    unsigned int mn = 0xFFFFFFFFu, mx = 0u;
#pragma unroll
    for (int k = 0; k < 32; ++k) {
        val[k] = w[b * F + k * 256 + t];
        const unsigned int u = __float_as_uint(val[k]);     // w>=0: bit-monotone
        mn = mn < u ? mn : u;
        mx = mx > u ? mx : u;
    }
#pragma unroll
    for (int off = 32; off > 0; off >>= 1) {
        const unsigned int o1 = __shfl_xor(mn, off, 64); mn = mn < o1 ? mn : o1;
        const unsigned int o2 = __shfl_xor(mx, off, 64); mx = mx > o2 ? mx : o2;
    }
    if (lane == 0) { redmn[wv] = mn; redmx[wv] = mx; }
    __syncthreads();                                        // [1]
    if (t == 0) {
        unsigned int a = redmn[0], c = redmx[0];
        for (int i = 1; i < 4; ++i) {
            a = a < redmn[i] ? a : redmn[i];
            c = c > redmx[i] ? c : redmx[i];
        }
        slo = a; shi = c;
    }
    __syncthreads();                                        // [2]
    const float lo    = __uint_as_float(slo);
    const float hi    = __uint_as_float(shi);
    const float scale = (float)(NB - 2) / fmaxf(hi - lo, 1e-30f);

#pragma unroll
    for (int k = 0; k < 32; ++k) atomicAdd(&h[binOf(val[k], lo, scale)], 1);
    __syncthreads();                                        // [3]

    int s = 0;
#pragma unroll
    for (int i = 0; i < 16; ++i) s += h[t * 16 + i];
    int incl = s;
#pragma unroll
    for (int off = 1; off < 64; off <<= 1) {
        const int u = __shfl_up(incl, off, 64);
        if (lane >= off) incl += u;
    }
    if (lane == 63) wsum[wv] = incl;
    __syncthreads();                                        // [4]
    int add = 0;
    for (int i = 0; i < wv; ++i) add += wsum[i];
    const int inclT = incl + add;
    const int exclT = inclT - s;
    if (P - 1 >= exclT && P - 1 < inclT) {                  // exactly one thread
        int c = exclT;
#pragma unroll
        for (int i = 0; i < 16; ++i) {
            const int bin = t * 16 + i;
            const int hv  = h[bin];
            if (P - 1 < c + hv) { sT = bin; sR = P - c; break; }
            c += hv;
        }
    }
    __syncthreads();                                        // [5]
    const int T = sT, R = sR;

    // scatter own 256 faces (full-width phase)
    const float myv = val[gg];
    const int face  = b * F + gg * 256 + t;
    if (binOf(myv, lo, scale) < T) {
        flag[face] = 1;
#pragma unroll
        for (int j = 0; j < 3; ++j) {
            const int n    = adj[(size_t)face * 3 + j];
            const int tgt  = b * F + n;
            const int slot = atomicAdd(&cnt[tgt], 1);
            if (slot < CAP) srcs[(size_t)tgt * CAP + slot] = face;
        }
    }

    // leader block: boundary-bin exact rank
    if (gg == 0) {                                          // block-uniform branch
#pragma unroll
        for (int k = 0; k < 32; ++k) {
            if (binOf(val[k], lo, scale) == T) {
                const int pos = atomicAdd(&scnt, 1);        // LDS atomic
                if (pos < CCAP)
                    carr[pos] = ((unsigned long long)__float_as_uint(val[k]) << 32) |
                                (uint32_t)(k * 256 + t);    // idx in [0,F)
            }
        }
        __syncthreads();                                    // leader-only: uniform
        const int n = scnt < CCAP ? scnt : CCAP;
        for (int i = t; i < n; i += 256) {
            const unsigned long long my = carr[i];
            int rank = 0;
            for (int j = 0; j < n; ++j) rank += (carr[j] < my) ? 1 : 0;
            if (rank < R) {                                 // keys distinct (idx bits)
                const int tt = b * F + (int)(uint32_t)my;
                flag[tt] = 1;
#pragma unroll
                for (int j = 0; j < 3; ++j) {
                    const int nb   = adj[(size_t)tt * 3 + j];
                    const int tgt  = b * F + nb;
                    const int slot = atomicAdd(&cnt[tgt], 1);
                    if (slot < CAP) srcs[(size_t)tgt * CAP + slot] = tt;
                }
            }
        }
    }
}

// ---------------------------------------------------------------------------
// kG: merge + normalize + erase. NEW (r8): TWO faces per wave — round-7
// counters showed the merge is latency-bound (1.95 TB/s, 24% peak), so
// double the independent dependent-chains per wave. Both srcs rows come in
// ONE load (lanes 0-15 = face A slots, 16-31 = face B). Flagged faces fold
// to mm=0 / acc=0 -> store is branchless zero. NT stores (r5).
// ---------------------------------------------------------------------------
__global__ __launch_bounds__(256) void kG(const float* __restrict__ feat,
                                          const int* __restrict__ cnt,
                                          const int* __restrict__ flag,
                                          const int* __restrict__ srcs,
                                          float* __restrict__ out) {
    const int b     = blockIdx.x & 7;                       // batch == XCD
    const int inner = blockIdx.x >> 3;                      // [0, 1024)
    const int wv    = threadIdx.x >> 6;
    const int lane  = threadIdx.x & 63;
    const int fA    = b * F + inner * 8 + wv * 2;           // wave's face pair
    const int fB    = fA + 1;

    const int flA = flag[fA], flB = flag[fB];
    const int mA  = cnt[fA],  mB  = cnt[fB];
    const int mmA = flA ? 0 : (mA < CAP ? mA : CAP);
    const int mmB = flB ? 0 : (mB < CAP ? mB : CAP);

    // both srcs rows in one load: lanes 0-15 -> A slots, 16-31 -> B slots
    int sidx = 0;
    if (lane < 32) {
        const int f = (lane < 16) ? fA : fB;
        sidx = srcs[(size_t)f * CAP + (lane & 15)];
    }

    const float4* rowA = (const float4*)(feat + (size_t)fA * C);
    const float4* rowB = (const float4*)(feat + (size_t)fB * C);
    float4 accA = {0.f, 0.f, 0.f, 0.f}, accB = {0.f, 0.f, 0.f, 0.f};
    if (!flA) accA = rowA[lane];                            // wave-uniform
    if (!flB) accB = rowB[lane];

    const float inv3 = 1.0f / 3.0f;
    const int mx = mmA > mmB ? mmA : mmB;
    for (int i = 0; i < mx; ++i) {                          // two chains in flight
        if (i < mmA) {                                      // wave-uniform
            const int s = __shfl(sidx, i, 64);
            const float4 v = ((const float4*)(feat + (size_t)s * C))[lane];
            accA.x += v.x * inv3; accA.y += v.y * inv3;
            accA.z += v.z * inv3; accA.w += v.w * inv3;
        }
        if (i < mmB) {
            const int s = __shfl(sidx, 16 + i, 64);
            const float4 v = ((const float4*)(feat + (size_t)s * C))[lane];
            accB.x += v.x * inv3; accB.y += v.y * inv3;
            accB.z += v.z * inv3; accB.w += v.w * inv3;
        }
    }
    const float invA = 1.0f / (1.0f + (float)mA);           // flA: acc=0 -> r=0
    const float invB = 1.0f / (1.0f + (float)mB);
    f32x4 rA, rB;
    rA.x = accA.x * invA; rA.y = accA.y * invA;
    rA.z = accA.z * invA; rA.w = accA.w * invA;
    rB.x = accB.x * invB; rB.y = accB.y * invB;
    rB.z = accB.z * invB; rB.w = accB.w * invB;
    __builtin_nontemporal_store(rA, &((f32x4*)(out + (size_t)fA * C))[lane]);
    __builtin_nontemporal_store(rB, &((f32x4*)(out + (size_t)fB * C))[lane]);
}

extern "C" void kernel_launch(void* const* d_in, const int* in_sizes, int n_in,
                              void* d_out, int out_size, void* d_ws, size_t ws_size,
                              hipStream_t stream) {
    const float* feat = (const float*)d_in[0];
    const int*   adj  = (const int*)d_in[1];
    const int*   ring = (const int*)d_in[2];
    float* out = (float*)d_out;

    // ws layout: w | cnt | flag | srcs
    float* w    = (float*)d_ws;                             // B*F
    int*   cnt  = (int*)(w + BF);                           // B*F
    int*   flag = cnt + BF;                                 // B*F
    int*   srcs = flag + BF;                                // B*F*CAP (4 MiB)

    kW  <<<BF / 4, 256, 0, stream>>>(feat, ring, w, cnt, flag);
    kFS <<<BF / 256, 256, 0, stream>>>(w, adj, flag, cnt, srcs);
    kG  <<<BF / 8, 256, 0, stream>>>(feat, cnt, flag, srcs, out);
}

// Round 9
// 152.664 us; speedup vs baseline: 1.0825x; 1.0067x over previous
//
#include <hip/hip_runtime.h>
#include <stdint.h>

#define B 8
#define F 8192
#define C 256
#define K 4
#define P (F / 4)     // 2048
#define CAP 16        // max tracked incoming collapsed faces per target
#define NB 4096       // linear bins over per-batch [lo, hi]
#define BF (B * F)
#define CCAP 1024     // leader LDS candidate capacity (bin==T pop ~ O(10))

typedef float f32x4 __attribute__((ext_vector_type(4)));

// Monotone, deterministic linear bin — identical expression in every block.
__device__ __forceinline__ int binOf(float v, float lo, float scale) {
    int bin = (int)((v - lo) * scale);
    return bin < 0 ? 0 : (bin > NB - 1 ? NB - 1 : bin);
}

// ---------------------------------------------------------------------------
// kW: one wave per face — gather K=4 ring rows, mean, L2 norm^2 -> w.
// (sqrt dropped: monotone — r4/r5.) Lane 0 zeroes cnt/flag.
// 256 MB gathered reads, bytes irreducible (norm-of-sum needs all K rows);
// r4 L2-blocking null => at its blended-BW floor. Leave alone.
// ---------------------------------------------------------------------------
__global__ __launch_bounds__(256) void kW(const float* __restrict__ feat,
                                          const int* __restrict__ ring,
                                          float* __restrict__ w,
                                          int* __restrict__ cnt,
                                          int* __restrict__ flag) {
    const int b     = blockIdx.x & 7;                       // batch == XCD
    const int inner = blockIdx.x >> 3;                      // [0, 2048)
    const int wid   = b * F + inner * 4 + (threadIdx.x >> 6);
    const int lane  = threadIdx.x & 63;

    const int rbase = wid * K;
    const int r0 = ring[rbase + 0], r1 = ring[rbase + 1];
    const int r2 = ring[rbase + 2], r3 = ring[rbase + 3];
    const float4* f4 = (const float4*)feat;
    const size_t base = (size_t)b * F;
    const int    CW   = C / 4;
    const float4 v0 = f4[(base + r0) * CW + lane];
    const float4 v1 = f4[(base + r1) * CW + lane];
    const float4 v2 = f4[(base + r2) * CW + lane];
    const float4 v3 = f4[(base + r3) * CW + lane];

    float4 a;
    a.x = (v0.x + v1.x) + (v2.x + v3.x);
    a.y = (v0.y + v1.y) + (v2.y + v3.y);
    a.z = (v0.z + v1.z) + (v2.z + v3.z);
    a.w = (v0.w + v1.w) + (v2.w + v3.w);
    float s = (a.x * a.x + a.y * a.y + a.z * a.z + a.w * a.w) * 0.0625f;
#pragma unroll
    for (int off = 32; off > 0; off >>= 1) s += __shfl_down(s, off, 64);
    if (lane == 0) {
        w[wid]    = s;                                      // norm^2 (monotone)
        cnt[wid]  = 0;
        flag[wid] = 0;
    }
}

// ---------------------------------------------------------------------------
// kFS: fused threshold + scatter + boundary-select (round-6, validated).
// 256 blocks x 256 thr; each block redundantly recomputes its batch's
// (T, R) from the full 32 KB w slice (bit-deterministic: fp min/max exact,
// hist/scan integer); scatters its own 256 faces at full GPU width; leader
// block per batch exact-ranks the bin==T boundary candidates.
// ---------------------------------------------------------------------------
__global__ __launch_bounds__(256) void kFS(const float* __restrict__ w,
                                           const int* __restrict__ adj,
                                           int* __restrict__ flag,
                                           int* __restrict__ cnt,
                                           int* __restrict__ srcs) {
    __shared__ int h[NB];                                   // 16 KiB
    __shared__ unsigned long long carr[CCAP];               // 8 KiB
    __shared__ unsigned int redmn[4], redmx[4];
    __shared__ int wsum[4];
    __shared__ unsigned int slo, shi;
    __shared__ int sT, sR, scnt;
    const int g    = blockIdx.x;
    const int b    = g >> 5;                                // batch
    const int gg   = g & 31;                                // block-in-batch
    const int t    = threadIdx.x;
    const int lane = t & 63, wv = t >> 6;

    if (t == 0) scnt = 0;
    for (int i = t; i < NB; i += 256) h[i] = 0;

    float val[32];
    unsigned int mn = 0xFFFFFFFFu, mx = 0u;
#pragma unroll
    for (int k = 0; k < 32; ++k) {
        val[k] = w[b * F + k * 256 + t];
        const unsigned int u = __float_as_uint(val[k]);     // w>=0: bit-monotone
        mn = mn < u ? mn : u;
        mx = mx > u ? mx : u;
    }
#pragma unroll
    for (int off = 32; off > 0; off >>= 1) {
        const unsigned int o1 = __shfl_xor(mn, off, 64); mn = mn < o1 ? mn : o1;
        const unsigned int o2 = __shfl_xor(mx, off, 64); mx = mx > o2 ? mx : o2;
    }
    if (lane == 0) { redmn[wv] = mn; redmx[wv] = mx; }
    __syncthreads();                                        // [1]
    if (t == 0) {
        unsigned int a = redmn[0], c = redmx[0];
        for (int i = 1; i < 4; ++i) {
            a = a < redmn[i] ? a : redmn[i];
            c = c > redmx[i] ? c : redmx[i];
        }
        slo = a; shi = c;
    }
    __syncthreads();                                        // [2]
    const float lo    = __uint_as_float(slo);
    const float hi    = __uint_as_float(shi);
    const float scale = (float)(NB - 2) / fmaxf(hi - lo, 1e-30f);

#pragma unroll
    for (int k = 0; k < 32; ++k) atomicAdd(&h[binOf(val[k], lo, scale)], 1);
    __syncthreads();                                        // [3]

    int s = 0;
#pragma unroll
    for (int i = 0; i < 16; ++i) s += h[t * 16 + i];
    int incl = s;
#pragma unroll
    for (int off = 1; off < 64; off <<= 1) {
        const int u = __shfl_up(incl, off, 64);
        if (lane >= off) incl += u;
    }
    if (lane == 63) wsum[wv] = incl;
    __syncthreads();                                        // [4]
    int add = 0;
    for (int i = 0; i < wv; ++i) add += wsum[i];
    const int inclT = incl + add;
    const int exclT = inclT - s;
    if (P - 1 >= exclT && P - 1 < inclT) {                  // exactly one thread
        int c = exclT;
#pragma unroll
        for (int i = 0; i < 16; ++i) {
            const int bin = t * 16 + i;
            const int hv  = h[bin];
            if (P - 1 < c + hv) { sT = bin; sR = P - c; break; }
            c += hv;
        }
    }
    __syncthreads();                                        // [5]
    const int T = sT, R = sR;

    // scatter own 256 faces (full-width phase)
    const float myv = val[gg];
    const int face  = b * F + gg * 256 + t;
    if (binOf(myv, lo, scale) < T) {
        flag[face] = 1;
#pragma unroll
        for (int j = 0; j < 3; ++j) {
            const int n    = adj[(size_t)face * 3 + j];
            const int tgt  = b * F + n;
            const int slot = atomicAdd(&cnt[tgt], 1);
            if (slot < CAP) srcs[(size_t)tgt * CAP + slot] = face;
        }
    }

    // leader block: boundary-bin exact rank
    if (gg == 0) {                                          // block-uniform branch
#pragma unroll
        for (int k = 0; k < 32; ++k) {
            if (binOf(val[k], lo, scale) == T) {
                const int pos = atomicAdd(&scnt, 1);        // LDS atomic
                if (pos < CCAP)
                    carr[pos] = ((unsigned long long)__float_as_uint(val[k]) << 32) |
                                (uint32_t)(k * 256 + t);    // idx in [0,F)
            }
        }
        __syncthreads();                                    // leader-only: uniform
        const int n = scnt < CCAP ? scnt : CCAP;
        for (int i = t; i < n; i += 256) {
            const unsigned long long my = carr[i];
            int rank = 0;
            for (int j = 0; j < n; ++j) rank += (carr[j] < my) ? 1 : 0;
            if (rank < R) {                                 // keys distinct (idx bits)
                const int tt = b * F + (int)(uint32_t)my;
                flag[tt] = 1;
#pragma unroll
                for (int j = 0; j < 3; ++j) {
                    const int nb   = adj[(size_t)tt * 3 + j];
                    const int tgt  = b * F + nb;
                    const int slot = atomicAdd(&cnt[tgt], 1);
                    if (slot < CAP) srcs[(size_t)tgt * CAP + slot] = tt;
                }
            }
        }
    }
}

// ---------------------------------------------------------------------------
// kG: merge + normalize + erase. r8 proved the merge is latency-limited
// (2-chain ILP -> -3 µs); r9 doubles again: FOUR faces per wave. All 64
// lanes now carry a srcs slot (4 faces x 16 slots = one fully-coalesced
// 256 B load), 4 accumulators, 4 interleaved gather chains. Flagged faces
// fold to mm=0 / acc=0 -> branchless zero store. NT stores (r5).
// ---------------------------------------------------------------------------
__global__ __launch_bounds__(256) void kG(const float* __restrict__ feat,
                                          const int* __restrict__ cnt,
                                          const int* __restrict__ flag,
                                          const int* __restrict__ srcs,
                                          float* __restrict__ out) {
    const int b     = blockIdx.x & 7;                       // batch == XCD
    const int inner = blockIdx.x >> 3;                      // [0, 512)
    const int wv    = threadIdx.x >> 6;
    const int lane  = threadIdx.x & 63;
    const int f0    = b * F + inner * 16 + wv * 4;          // wave's 4 faces

    int fl[4], m[4], mm[4];
#pragma unroll
    for (int q = 0; q < 4; ++q) {
        fl[q] = flag[f0 + q];
        m[q]  = cnt[f0 + q];
        mm[q] = fl[q] ? 0 : (m[q] < CAP ? m[q] : CAP);
    }

    // one coalesced 256 B load: lane q*16+s holds slot s of face f0+q
    const int sidx = srcs[(size_t)(f0 + (lane >> 4)) * CAP + (lane & 15)];

    float4 acc[4];
#pragma unroll
    for (int q = 0; q < 4; ++q) {
        acc[q] = make_float4(0.f, 0.f, 0.f, 0.f);
        if (!fl[q])                                         // wave-uniform
            acc[q] = ((const float4*)(feat + (size_t)(f0 + q) * C))[lane];
    }

    const float inv3 = 1.0f / 3.0f;
    int mx = mm[0];
#pragma unroll
    for (int q = 1; q < 4; ++q) mx = mm[q] > mx ? mm[q] : mx;
    for (int i = 0; i < mx; ++i) {                          // 4 chains in flight
#pragma unroll
        for (int q = 0; q < 4; ++q) {
            if (i < mm[q]) {                                // wave-uniform
                const int s = __shfl(sidx, q * 16 + i, 64);
                const float4 v = ((const float4*)(feat + (size_t)s * C))[lane];
                acc[q].x += v.x * inv3; acc[q].y += v.y * inv3;
                acc[q].z += v.z * inv3; acc[q].w += v.w * inv3;
            }
        }
    }
#pragma unroll
    for (int q = 0; q < 4; ++q) {                           // fl: acc=0 -> r=0
        const float inv = 1.0f / (1.0f + (float)m[q]);
        f32x4 r;
        r.x = acc[q].x * inv; r.y = acc[q].y * inv;
        r.z = acc[q].z * inv; r.w = acc[q].w * inv;
        __builtin_nontemporal_store(r, &((f32x4*)(out + (size_t)(f0 + q) * C))[lane]);
    }
}

extern "C" void kernel_launch(void* const* d_in, const int* in_sizes, int n_in,
                              void* d_out, int out_size, void* d_ws, size_t ws_size,
                              hipStream_t stream) {
    const float* feat = (const float*)d_in[0];
    const int*   adj  = (const int*)d_in[1];
    const int*   ring = (const int*)d_in[2];
    float* out = (float*)d_out;

    // ws layout: w | cnt | flag | srcs
    float* w    = (float*)d_ws;                             // B*F
    int*   cnt  = (int*)(w + BF);                           // B*F
    int*   flag = cnt + BF;                                 // B*F
    int*   srcs = flag + BF;                                // B*F*CAP (4 MiB)

    kW  <<<BF / 4, 256, 0, stream>>>(feat, ring, w, cnt, flag);
    kFS <<<BF / 256, 256, 0, stream>>>(w, adj, flag, cnt, srcs);
    kG  <<<BF / 16, 256, 0, stream>>>(feat, cnt, flag, srcs, out);
}

// Round 10
// 151.563 us; speedup vs baseline: 1.0903x; 1.0073x over previous
//
#include <hip/hip_runtime.h>
#include <stdint.h>

#define B 8
#define F 8192
#define C 256
#define K 4
#define P (F / 4)     // 2048
#define CAP 16        // max tracked incoming collapsed faces per target
#define NB 4096       // linear bins over per-batch [lo, hi]
#define BF (B * F)
#define CCAP 1024     // leader LDS candidate capacity (bin==T pop ~ O(10))

typedef float f32x4 __attribute__((ext_vector_type(4)));

// Monotone, deterministic linear bin — identical expression in every block.
__device__ __forceinline__ int binOf(float v, float lo, float scale) {
    int bin = (int)((v - lo) * scale);
    return bin < 0 ? 0 : (bin > NB - 1 ? NB - 1 : bin);
}

// ---------------------------------------------------------------------------
// kW: r10 — TWO faces per wave (8 independent 1 KB row-gathers in flight,
// 2x outstanding bytes vs r9). Rationale: the harness's 256 MiB ws poison
// evicts L3 between iterations, so kW's floor is ~64 MB HBM + ~192 MB L3
// ~= 20 µs; r4 showed cache-level blocking is neutral -> concurrency is
// the remaining lever (same diagnosis that won in kG r8). Two shfl-reduce
// trees; lane 0 writes both w / cnt / flag pairs.
// ---------------------------------------------------------------------------
__global__ __launch_bounds__(256) void kW(const float* __restrict__ feat,
                                          const int* __restrict__ ring,
                                          float* __restrict__ w,
                                          int* __restrict__ cnt,
                                          int* __restrict__ flag) {
    const int b     = blockIdx.x & 7;                       // batch == XCD
    const int inner = blockIdx.x >> 3;                      // [0, 1024)
    const int wv    = threadIdx.x >> 6;
    const int lane  = threadIdx.x & 63;
    const int fA    = b * F + inner * 8 + wv * 2;           // wave's face pair
    const int fB    = fA + 1;

    const int ra = fA * K, rb = fB * K;
    int r[8];
#pragma unroll
    for (int j = 0; j < 4; ++j) { r[j] = ring[ra + j]; r[4 + j] = ring[rb + j]; }

    const float4* f4 = (const float4*)feat;
    const size_t base = (size_t)b * F;
    const int    CW   = C / 4;
    float4 v[8];
#pragma unroll
    for (int j = 0; j < 8; ++j) v[j] = f4[(base + r[j]) * CW + lane];

    float4 a, c;
    a.x = (v[0].x + v[1].x) + (v[2].x + v[3].x);
    a.y = (v[0].y + v[1].y) + (v[2].y + v[3].y);
    a.z = (v[0].z + v[1].z) + (v[2].z + v[3].z);
    a.w = (v[0].w + v[1].w) + (v[2].w + v[3].w);
    c.x = (v[4].x + v[5].x) + (v[6].x + v[7].x);
    c.y = (v[4].y + v[5].y) + (v[6].y + v[7].y);
    c.z = (v[4].z + v[5].z) + (v[6].z + v[7].z);
    c.w = (v[4].w + v[5].w) + (v[6].w + v[7].w);
    float sA = (a.x * a.x + a.y * a.y + a.z * a.z + a.w * a.w) * 0.0625f;
    float sB = (c.x * c.x + c.y * c.y + c.z * c.z + c.w * c.w) * 0.0625f;
#pragma unroll
    for (int off = 32; off > 0; off >>= 1) {
        sA += __shfl_down(sA, off, 64);
        sB += __shfl_down(sB, off, 64);
    }
    if (lane == 0) {
        w[fA] = sA;  w[fB] = sB;                            // norm^2 (monotone)
        cnt[fA] = 0; cnt[fB] = 0;
        flag[fA] = 0; flag[fB] = 0;
    }
}

// ---------------------------------------------------------------------------
// kFS: fused threshold + scatter + boundary-select (round-6, validated).
// 256 blocks x 256 thr; each block redundantly recomputes its batch's
// (T, R) from the full 32 KB w slice (bit-deterministic: fp min/max exact,
// hist/scan integer); scatters its own 256 faces at full GPU width; leader
// block per batch exact-ranks the bin==T boundary candidates.
// ---------------------------------------------------------------------------
__global__ __launch_bounds__(256) void kFS(const float* __restrict__ w,
                                           const int* __restrict__ adj,
                                           int* __restrict__ flag,
                                           int* __restrict__ cnt,
                                           int* __restrict__ srcs) {
    __shared__ int h[NB];                                   // 16 KiB
    __shared__ unsigned long long carr[CCAP];               // 8 KiB
    __shared__ unsigned int redmn[4], redmx[4];
    __shared__ int wsum[4];
    __shared__ unsigned int slo, shi;
    __shared__ int sT, sR, scnt;
    const int g    = blockIdx.x;
    const int b    = g >> 5;                                // batch
    const int gg   = g & 31;                                // block-in-batch
    const int t    = threadIdx.x;
    const int lane = t & 63, wv = t >> 6;

    if (t == 0) scnt = 0;
    for (int i = t; i < NB; i += 256) h[i] = 0;

    float val[32];
    unsigned int mn = 0xFFFFFFFFu, mx = 0u;
#pragma unroll
    for (int k = 0; k < 32; ++k) {
        val[k] = w[b * F + k * 256 + t];
        const unsigned int u = __float_as_uint(val[k]);     // w>=0: bit-monotone
        mn = mn < u ? mn : u;
        mx = mx > u ? mx : u;
    }
#pragma unroll
    for (int off = 32; off > 0; off >>= 1) {
        const unsigned int o1 = __shfl_xor(mn, off, 64); mn = mn < o1 ? mn : o1;
        const unsigned int o2 = __shfl_xor(mx, off, 64); mx = mx > o2 ? mx : o2;
    }
    if (lane == 0) { redmn[wv] = mn; redmx[wv] = mx; }
    __syncthreads();                                        // [1]
    if (t == 0) {
        unsigned int a = redmn[0], c = redmx[0];
        for (int i = 1; i < 4; ++i) {
            a = a < redmn[i] ? a : redmn[i];
            c = c > redmx[i] ? c : redmx[i];
        }
        slo = a; shi = c;
    }
    __syncthreads();                                        // [2]
    const float lo    = __uint_as_float(slo);
    const float hi    = __uint_as_float(shi);
    const float scale = (float)(NB - 2) / fmaxf(hi - lo, 1e-30f);

#pragma unroll
    for (int k = 0; k < 32; ++k) atomicAdd(&h[binOf(val[k], lo, scale)], 1);
    __syncthreads();                                        // [3]

    int s = 0;
#pragma unroll
    for (int i = 0; i < 16; ++i) s += h[t * 16 + i];
    int incl = s;
#pragma unroll
    for (int off = 1; off < 64; off <<= 1) {
        const int u = __shfl_up(incl, off, 64);
        if (lane >= off) incl += u;
    }
    if (lane == 63) wsum[wv] = incl;
    __syncthreads();                                        // [4]
    int add = 0;
    for (int i = 0; i < wv; ++i) add += wsum[i];
    const int inclT = incl + add;
    const int exclT = inclT - s;
    if (P - 1 >= exclT && P - 1 < inclT) {                  // exactly one thread
        int c = exclT;
#pragma unroll
        for (int i = 0; i < 16; ++i) {
            const int bin = t * 16 + i;
            const int hv  = h[bin];
            if (P - 1 < c + hv) { sT = bin; sR = P - c; break; }
            c += hv;
        }
    }
    __syncthreads();                                        // [5]
    const int T = sT, R = sR;

    // scatter own 256 faces (full-width phase)
    const float myv = val[gg];
    const int face  = b * F + gg * 256 + t;
    if (binOf(myv, lo, scale) < T) {
        flag[face] = 1;
#pragma unroll
        for (int j = 0; j < 3; ++j) {
            const int n    = adj[(size_t)face * 3 + j];
            const int tgt  = b * F + n;
            const int slot = atomicAdd(&cnt[tgt], 1);
            if (slot < CAP) srcs[(size_t)tgt * CAP + slot] = face;
        }
    }

    // leader block: boundary-bin exact rank
    if (gg == 0) {                                          // block-uniform branch
#pragma unroll
        for (int k = 0; k < 32; ++k) {
            if (binOf(val[k], lo, scale) == T) {
                const int pos = atomicAdd(&scnt, 1);        // LDS atomic
                if (pos < CCAP)
                    carr[pos] = ((unsigned long long)__float_as_uint(val[k]) << 32) |
                                (uint32_t)(k * 256 + t);    // idx in [0,F)
            }
        }
        __syncthreads();                                    // leader-only: uniform
        const int n = scnt < CCAP ? scnt : CCAP;
        for (int i = t; i < n; i += 256) {
            const unsigned long long my = carr[i];
            int rank = 0;
            for (int j = 0; j < n; ++j) rank += (carr[j] < my) ? 1 : 0;
            if (rank < R) {                                 // keys distinct (idx bits)
                const int tt = b * F + (int)(uint32_t)my;
                flag[tt] = 1;
#pragma unroll
                for (int j = 0; j < 3; ++j) {
                    const int nb   = adj[(size_t)tt * 3 + j];
                    const int tgt  = b * F + nb;
                    const int slot = atomicAdd(&cnt[tgt], 1);
                    if (slot < CAP) srcs[(size_t)tgt * CAP + slot] = tt;
                }
            }
        }
    }
}

// ---------------------------------------------------------------------------
// kG: merge + normalize + erase — FOUR faces per wave (r9, at its floor).
// All 64 lanes carry a srcs slot (one coalesced 256 B load), 4 accumulators,
// 4 interleaved gather chains. Flagged faces fold to mm=0 / acc=0 ->
// branchless zero store. NT stores (r5).
// ---------------------------------------------------------------------------
__global__ __launch_bounds__(256) void kG(const float* __restrict__ feat,
                                          const int* __restrict__ cnt,
                                          const int* __restrict__ flag,
                                          const int* __restrict__ srcs,
                                          float* __restrict__ out) {
    const int b     = blockIdx.x & 7;                       // batch == XCD
    const int inner = blockIdx.x >> 3;                      // [0, 512)
    const int wv    = threadIdx.x >> 6;
    const int lane  = threadIdx.x & 63;
    const int f0    = b * F + inner * 16 + wv * 4;          // wave's 4 faces

    int fl[4], m[4], mm[4];
#pragma unroll
    for (int q = 0; q < 4; ++q) {
        fl[q] = flag[f0 + q];
        m[q]  = cnt[f0 + q];
        mm[q] = fl[q] ? 0 : (m[q] < CAP ? m[q] : CAP);
    }

    // one coalesced 256 B load: lane q*16+s holds slot s of face f0+q
    const int sidx = srcs[(size_t)(f0 + (lane >> 4)) * CAP + (lane & 15)];

    float4 acc[4];
#pragma unroll
    for (int q = 0; q < 4; ++q) {
        acc[q] = make_float4(0.f, 0.f, 0.f, 0.f);
        if (!fl[q])                                         // wave-uniform
            acc[q] = ((const float4*)(feat + (size_t)(f0 + q) * C))[lane];
    }

    const float inv3 = 1.0f / 3.0f;
    int mx = mm[0];
#pragma unroll
    for (int q = 1; q < 4; ++q) mx = mm[q] > mx ? mm[q] : mx;
    for (int i = 0; i < mx; ++i) {                          // 4 chains in flight
#pragma unroll
        for (int q = 0; q < 4; ++q) {
            if (i < mm[q]) {                                // wave-uniform
                const int s = __shfl(sidx, q * 16 + i, 64);
                const float4 v = ((const float4*)(feat + (size_t)s * C))[lane];
                acc[q].x += v.x * inv3; acc[q].y += v.y * inv3;
                acc[q].z += v.z * inv3; acc[q].w += v.w * inv3;
            }
        }
    }
#pragma unroll
    for (int q = 0; q < 4; ++q) {                           // fl: acc=0 -> r=0
        const float inv = 1.0f / (1.0f + (float)m[q]);
        f32x4 r;
        r.x = acc[q].x * inv; r.y = acc[q].y * inv;
        r.z = acc[q].z * inv; r.w = acc[q].w * inv;
        __builtin_nontemporal_store(r, &((f32x4*)(out + (size_t)(f0 + q) * C))[lane]);
    }
}

extern "C" void kernel_launch(void* const* d_in, const int* in_sizes, int n_in,
                              void* d_out, int out_size, void* d_ws, size_t ws_size,
                              hipStream_t stream) {
    const float* feat = (const float*)d_in[0];
    const int*   adj  = (const int*)d_in[1];
    const int*   ring = (const int*)d_in[2];
    float* out = (float*)d_out;

    // ws layout: w | cnt | flag | srcs
    float* w    = (float*)d_ws;                             // B*F
    int*   cnt  = (int*)(w + BF);                           // B*F
    int*   flag = cnt + BF;                                 // B*F
    int*   srcs = flag + BF;                                // B*F*CAP (4 MiB)

    kW  <<<BF / 8, 256, 0, stream>>>(feat, ring, w, cnt, flag);
    kFS <<<BF / 256, 256, 0, stream>>>(w, adj, flag, cnt, srcs);
    kG  <<<BF / 16, 256, 0, stream>>>(feat, cnt, flag, srcs, out);
}

// Round 11
// 149.960 us; speedup vs baseline: 1.1020x; 1.0107x over previous
//
#include <hip/hip_runtime.h>
#include <stdint.h>

#define B 8
#define F 8192
#define C 256
#define K 4
#define P (F / 4)     // 2048
#define CAP 16        // max tracked incoming collapsed faces per target
#define NB 2048       // linear bins over per-batch [lo, hi] (r11: halved)
#define BF (B * F)
#define CCAP 1024     // leader LDS candidate capacity (bin==T pop ~ O(20))

typedef float f32x4 __attribute__((ext_vector_type(4)));

// Monotone, deterministic linear bin — identical expression in every block.
__device__ __forceinline__ int binOf(float v, float lo, float scale) {
    int bin = (int)((v - lo) * scale);
    return bin < 0 ? 0 : (bin > NB - 1 ? NB - 1 : bin);
}

// ---------------------------------------------------------------------------
// kW: r11 — FOUR faces per wave (16 independent 1 KB row-gathers in flight).
// kW is bound by aggregate cache-line transaction rate (~7 TB/s blended —
// r4 tier-blocking null, r10 ILP +1µs); this is the last ILP step: 5
// waves/SIMD x 16 rows = 80 outstanding vs 64 at r10.
// ---------------------------------------------------------------------------
__global__ __launch_bounds__(256) void kW(const float* __restrict__ feat,
                                          const int* __restrict__ ring,
                                          float* __restrict__ w,
                                          int* __restrict__ cnt,
                                          int* __restrict__ flag) {
    const int b     = blockIdx.x & 7;                       // batch == XCD
    const int inner = blockIdx.x >> 3;                      // [0, 512)
    const int wv    = threadIdx.x >> 6;
    const int lane  = threadIdx.x & 63;
    const int f0    = b * F + inner * 16 + wv * 4;          // wave's 4 faces

    int r[16];
#pragma unroll
    for (int q = 0; q < 4; ++q) {
        const int rb = (f0 + q) * K;
#pragma unroll
        for (int j = 0; j < 4; ++j) r[q * 4 + j] = ring[rb + j];
    }

    const float4* f4 = (const float4*)feat;
    const size_t base = (size_t)b * F;
    const int    CW   = C / 4;
    float4 v[16];
#pragma unroll
    for (int j = 0; j < 16; ++j) v[j] = f4[(base + r[j]) * CW + lane];

    float s[4];
#pragma unroll
    for (int q = 0; q < 4; ++q) {
        float4 a;
        a.x = (v[q*4+0].x + v[q*4+1].x) + (v[q*4+2].x + v[q*4+3].x);
        a.y = (v[q*4+0].y + v[q*4+1].y) + (v[q*4+2].y + v[q*4+3].y);
        a.z = (v[q*4+0].z + v[q*4+1].z) + (v[q*4+2].z + v[q*4+3].z);
        a.w = (v[q*4+0].w + v[q*4+1].w) + (v[q*4+2].w + v[q*4+3].w);
        s[q] = (a.x * a.x + a.y * a.y + a.z * a.z + a.w * a.w) * 0.0625f;
    }
#pragma unroll
    for (int off = 32; off > 0; off >>= 1) {
#pragma unroll
        for (int q = 0; q < 4; ++q) s[q] += __shfl_down(s[q], off, 64);
    }
    if (lane == 0) {
#pragma unroll
        for (int q = 0; q < 4; ++q) {
            w[f0 + q]    = s[q];                            // norm^2 (monotone)
            cnt[f0 + q]  = 0;
            flag[f0 + q] = 0;
        }
    }
}

// ---------------------------------------------------------------------------
// kFS: fused threshold + scatter + boundary-select (round-6, validated).
// r11: NB halved to 2048 — halves the h-zero + scan cost paid redundantly
// by all 256 blocks; threshold-bin population ~14, still trivial for the
// leader's O(n^2) rank. Bit-deterministic across blocks (fp min/max exact,
// hist/scan integer, identical binOf everywhere).
// ---------------------------------------------------------------------------
__global__ __launch_bounds__(256) void kFS(const float* __restrict__ w,
                                           const int* __restrict__ adj,
                                           int* __restrict__ flag,
                                           int* __restrict__ cnt,
                                           int* __restrict__ srcs) {
    __shared__ int h[NB];                                   // 8 KiB
    __shared__ unsigned long long carr[CCAP];               // 8 KiB
    __shared__ unsigned int redmn[4], redmx[4];
    __shared__ int wsum[4];
    __shared__ unsigned int slo, shi;
    __shared__ int sT, sR, scnt;
    const int g    = blockIdx.x;
    const int b    = g >> 5;                                // batch
    const int gg   = g & 31;                                // block-in-batch
    const int t    = threadIdx.x;
    const int lane = t & 63, wv = t >> 6;

    if (t == 0) scnt = 0;
    for (int i = t; i < NB; i += 256) h[i] = 0;

    float val[32];
    unsigned int mn = 0xFFFFFFFFu, mx = 0u;
#pragma unroll
    for (int k = 0; k < 32; ++k) {
        val[k] = w[b * F + k * 256 + t];
        const unsigned int u = __float_as_uint(val[k]);     // w>=0: bit-monotone
        mn = mn < u ? mn : u;
        mx = mx > u ? mx : u;
    }
#pragma unroll
    for (int off = 32; off > 0; off >>= 1) {
        const unsigned int o1 = __shfl_xor(mn, off, 64); mn = mn < o1 ? mn : o1;
        const unsigned int o2 = __shfl_xor(mx, off, 64); mx = mx > o2 ? mx : o2;
    }
    if (lane == 0) { redmn[wv] = mn; redmx[wv] = mx; }
    __syncthreads();                                        // [1]
    if (t == 0) {
        unsigned int a = redmn[0], c = redmx[0];
        for (int i = 1; i < 4; ++i) {
            a = a < redmn[i] ? a : redmn[i];
            c = c > redmx[i] ? c : redmx[i];
        }
        slo = a; shi = c;
    }
    __syncthreads();                                        // [2]
    const float lo    = __uint_as_float(slo);
    const float hi    = __uint_as_float(shi);
    const float scale = (float)(NB - 2) / fmaxf(hi - lo, 1e-30f);

#pragma unroll
    for (int k = 0; k < 32; ++k) atomicAdd(&h[binOf(val[k], lo, scale)], 1);
    __syncthreads();                                        // [3]

    int s = 0;
#pragma unroll
    for (int i = 0; i < 8; ++i) s += h[t * 8 + i];          // 8 bins/thread
    int incl = s;
#pragma unroll
    for (int off = 1; off < 64; off <<= 1) {
        const int u = __shfl_up(incl, off, 64);
        if (lane >= off) incl += u;
    }
    if (lane == 63) wsum[wv] = incl;
    __syncthreads();                                        // [4]
    int add = 0;
    for (int i = 0; i < wv; ++i) add += wsum[i];
    const int inclT = incl + add;
    const int exclT = inclT - s;
    if (P - 1 >= exclT && P - 1 < inclT) {                  // exactly one thread
        int c = exclT;
#pragma unroll
        for (int i = 0; i < 8; ++i) {
            const int bin = t * 8 + i;
            const int hv  = h[bin];
            if (P - 1 < c + hv) { sT = bin; sR = P - c; break; }
            c += hv;
        }
    }
    __syncthreads();                                        // [5]
    const int T = sT, R = sR;

    // scatter own 256 faces (full-width phase)
    const float myv = val[gg];
    const int face  = b * F + gg * 256 + t;
    if (binOf(myv, lo, scale) < T) {
        flag[face] = 1;
#pragma unroll
        for (int j = 0; j < 3; ++j) {
            const int n    = adj[(size_t)face * 3 + j];
            const int tgt  = b * F + n;
            const int slot = atomicAdd(&cnt[tgt], 1);
            if (slot < CAP) srcs[(size_t)tgt * CAP + slot] = face;
        }
    }

    // leader block: boundary-bin exact rank
    if (gg == 0) {                                          // block-uniform branch
#pragma unroll
        for (int k = 0; k < 32; ++k) {
            if (binOf(val[k], lo, scale) == T) {
                const int pos = atomicAdd(&scnt, 1);        // LDS atomic
                if (pos < CCAP)
                    carr[pos] = ((unsigned long long)__float_as_uint(val[k]) << 32) |
                                (uint32_t)(k * 256 + t);    // idx in [0,F)
            }
        }
        __syncthreads();                                    // leader-only: uniform
        const int n = scnt < CCAP ? scnt : CCAP;
        for (int i = t; i < n; i += 256) {
            const unsigned long long my = carr[i];
            int rank = 0;
            for (int j = 0; j < n; ++j) rank += (carr[j] < my) ? 1 : 0;
            if (rank < R) {                                 // keys distinct (idx bits)
                const int tt = b * F + (int)(uint32_t)my;
                flag[tt] = 1;
#pragma unroll
                for (int j = 0; j < 3; ++j) {
                    const int nb   = adj[(size_t)tt * 3 + j];
                    const int tgt  = b * F + nb;
                    const int slot = atomicAdd(&cnt[tgt], 1);
                    if (slot < CAP) srcs[(size_t)tgt * CAP + slot] = tt;
                }
            }
        }
    }
}

// ---------------------------------------------------------------------------
// kG: merge + normalize + erase — FOUR faces per wave (r9, at its floor).
// All 64 lanes carry a srcs slot (one coalesced 256 B load), 4 accumulators,
// 4 interleaved gather chains. Flagged faces fold to mm=0 / acc=0 ->
// branchless zero store. NT stores (r5).
// ---------------------------------------------------------------------------
__global__ __launch_bounds__(256) void kG(const float* __restrict__ feat,
                                          const int* __restrict__ cnt,
                                          const int* __restrict__ flag,
                                          const int* __restrict__ srcs,
                                          float* __restrict__ out) {
    const int b     = blockIdx.x & 7;                       // batch == XCD
    const int inner = blockIdx.x >> 3;                      // [0, 512)
    const int wv    = threadIdx.x >> 6;
    const int lane  = threadIdx.x & 63;
    const int f0    = b * F + inner * 16 + wv * 4;          // wave's 4 faces

    int fl[4], m[4], mm[4];
#pragma unroll
    for (int q = 0; q < 4; ++q) {
        fl[q] = flag[f0 + q];
        m[q]  = cnt[f0 + q];
        mm[q] = fl[q] ? 0 : (m[q] < CAP ? m[q] : CAP);
    }

    // one coalesced 256 B load: lane q*16+s holds slot s of face f0+q
    const int sidx = srcs[(size_t)(f0 + (lane >> 4)) * CAP + (lane & 15)];

    float4 acc[4];
#pragma unroll
    for (int q = 0; q < 4; ++q) {
        acc[q] = make_float4(0.f, 0.f, 0.f, 0.f);
        if (!fl[q])                                         // wave-uniform
            acc[q] = ((const float4*)(feat + (size_t)(f0 + q) * C))[lane];
    }

    const float inv3 = 1.0f / 3.0f;
    int mx = mm[0];
#pragma unroll
    for (int q = 1; q < 4; ++q) mx = mm[q] > mx ? mm[q] : mx;
    for (int i = 0; i < mx; ++i) {                          // 4 chains in flight
#pragma unroll
        for (int q = 0; q < 4; ++q) {
            if (i < mm[q]) {                                // wave-uniform
                const int s = __shfl(sidx, q * 16 + i, 64);
                const float4 v = ((const float4*)(feat + (size_t)s * C))[lane];
                acc[q].x += v.x * inv3; acc[q].y += v.y * inv3;
                acc[q].z += v.z * inv3; acc[q].w += v.w * inv3;
            }
        }
    }
#pragma unroll
    for (int q = 0; q < 4; ++q) {                           // fl: acc=0 -> r=0
        const float inv = 1.0f / (1.0f + (float)m[q]);
        f32x4 r;
        r.x = acc[q].x * inv; r.y = acc[q].y * inv;
        r.z = acc[q].z * inv; r.w = acc[q].w * inv;
        __builtin_nontemporal_store(r, &((f32x4*)(out + (size_t)(f0 + q) * C))[lane]);
    }
}

extern "C" void kernel_launch(void* const* d_in, const int* in_sizes, int n_in,
                              void* d_out, int out_size, void* d_ws, size_t ws_size,
                              hipStream_t stream) {
    const float* feat = (const float*)d_in[0];
    const int*   adj  = (const int*)d_in[1];
    const int*   ring = (const int*)d_in[2];
    float* out = (float*)d_out;

    // ws layout: w | cnt | flag | srcs
    float* w    = (float*)d_ws;                             // B*F
    int*   cnt  = (int*)(w + BF);                           // B*F
    int*   flag = cnt + BF;                                 // B*F
    int*   srcs = flag + BF;                                // B*F*CAP (4 MiB)

    kW  <<<BF / 16, 256, 0, stream>>>(feat, ring, w, cnt, flag);
    kFS <<<BF / 256, 256, 0, stream>>>(w, adj, flag, cnt, srcs);
    kG  <<<BF / 16, 256, 0, stream>>>(feat, cnt, flag, srcs, out);
}